// Round 6
// baseline (1248.831 us; speedup 1.0000x reference)
//
#include <hip/hip_runtime.h>
#include <hip/hip_bf16.h>

#define T_SEQ 2048
#define HID   1024
#define NH    16
#define HD    64
#define NB    2

typedef __bf16 bf16_t;
typedef bf16_t bf16x8 __attribute__((ext_vector_type(8)));
typedef bf16_t bf16x4 __attribute__((ext_vector_type(4)));
typedef float  f32x4  __attribute__((ext_vector_type(4)));

static __device__ __forceinline__ f32x4 mfma16(bf16x8 a, bf16x8 b, f32x4 c) {
    return __builtin_amdgcn_mfma_f32_16x16x32_bf16(a, b, c, 0, 0, 0);
}

// One-time f32 -> bf16 conversion (same round-to-nearest as in-register path).
__global__ __launch_bounds__(256) void f32_to_bf16(const float* __restrict__ in,
                                                   bf16_t* __restrict__ out, int n8) {
    const int i = blockIdx.x * 256 + threadIdx.x;
    if (i < n8) {
        const float4* p = (const float4*)(in + (size_t)i * 8);
        float4 a0 = p[0], a1 = p[1];
        bf16x8 v;
        v[0]=(bf16_t)a0.x; v[1]=(bf16_t)a0.y; v[2]=(bf16_t)a0.z; v[3]=(bf16_t)a0.w;
        v[4]=(bf16_t)a1.x; v[5]=(bf16_t)a1.y; v[6]=(bf16_t)a1.z; v[7]=(bf16_t)a1.w;
        *(bf16x8*)(out + (size_t)i * 8) = v;
    }
}

// C[M x 1024] = A[M x 1024] @ W^T, W row-major (torch Linear).
// AMODE 0: A f32 (convert in-register). AMODE 1: A bf16.
// OMODE 0: bf16 [M][1024]. OMODE 1: bf16 transposed to [B][H][D][T] (V). OMODE 2: f32.
template<int AMODE, int OMODE>
__global__ __launch_bounds__(256) void gemm_xw(const void* __restrict__ Av,
                                               const float* __restrict__ W,
                                               void* __restrict__ outv, int M, int cpx) {
    const int hw = blockIdx.x;
    const int logical = (hw & 7) * cpx + (hw >> 3);
    const int wid  = logical * 4 + (threadIdx.x >> 6);
    const int lane = threadIdx.x & 63;
    const int mt = wid / 16, nt = wid % 16;
    const int row0 = mt * 64, col0 = nt * 64;
    const int lr = lane & 15;
    const int kd = (lane >> 4) * 8;

    f32x4 acc[4][4] = {};

    for (int k = 0; k < HID; k += 32) {
        bf16x8 af[4], bq[4];
#pragma unroll
        for (int i = 0; i < 4; ++i) {
            if (AMODE == 0) {
                const float* ap = (const float*)Av + (size_t)(row0 + i*16 + lr) * HID + k + kd;
                float4 a0 = *(const float4*)ap;
                float4 a1 = *(const float4*)(ap + 4);
                af[i][0]=(bf16_t)a0.x; af[i][1]=(bf16_t)a0.y; af[i][2]=(bf16_t)a0.z; af[i][3]=(bf16_t)a0.w;
                af[i][4]=(bf16_t)a1.x; af[i][5]=(bf16_t)a1.y; af[i][6]=(bf16_t)a1.z; af[i][7]=(bf16_t)a1.w;
            } else {
                af[i] = *(const bf16x8*)((const bf16_t*)Av + (size_t)(row0 + i*16 + lr) * HID + k + kd);
            }
        }
#pragma unroll
        for (int j = 0; j < 4; ++j) {
            const float* wp = W + (size_t)(col0 + j*16 + lr) * HID + k + kd;
            float4 b0 = *(const float4*)wp;
            float4 b1 = *(const float4*)(wp + 4);
            bq[j][0]=(bf16_t)b0.x; bq[j][1]=(bf16_t)b0.y; bq[j][2]=(bf16_t)b0.z; bq[j][3]=(bf16_t)b0.w;
            bq[j][4]=(bf16_t)b1.x; bq[j][5]=(bf16_t)b1.y; bq[j][6]=(bf16_t)b1.z; bq[j][7]=(bf16_t)b1.w;
        }
#pragma unroll
        for (int i = 0; i < 4; ++i)
#pragma unroll
            for (int j = 0; j < 4; ++j)
                acc[i][j] = mfma16(af[i], bq[j], acc[i][j]);
    }

    const int rb = (lane >> 4) * 4;
#pragma unroll
    for (int i = 0; i < 4; ++i) {
#pragma unroll
        for (int j = 0; j < 4; ++j) {
            const int col = col0 + j*16 + lr;
            if (OMODE == 0) {
                bf16_t* ob = (bf16_t*)outv;
#pragma unroll
                for (int r = 0; r < 4; ++r)
                    ob[(size_t)(row0 + i*16 + rb + r) * HID + col] = (bf16_t)acc[i][j][r];
            } else if (OMODE == 1) {
                const int row = row0 + i*16 + rb;
                const int bb = row >> 11, t = row & (T_SEQ - 1);
                const int hh = col >> 6,  d = col & 63;
                bf16x4 pk;
#pragma unroll
                for (int r = 0; r < 4; ++r) pk[r] = (bf16_t)acc[i][j][r];
                *(bf16x4*)((bf16_t*)outv + ((size_t)((bb*NH + hh)*HD + d))*T_SEQ + t) = pk;
            } else {
                float* of = (float*)outv;
#pragma unroll
                for (int r = 0; r < 4; ++r)
                    of[(size_t)(row0 + i*16 + rb + r) * HID + col] = acc[i][j][r];
            }
        }
    }
}

// Fused rel-shift attention, SWAPPED orientation, optional KV-split.
// __launch_bounds__(256,4): min 4 waves/EU -> unified VGPR+AGPR <=128/wave.
// (Rounds 1-5: ~190 unified regs -> 2 waves/SIMD -> occupancy pinned at 23%
// regardless of LDS/grid; this is the experiment that tests that theory.)
// NSPLIT=2: grid 2048, each block does half the s-range, stores unnormalized
// O (f32) + m,l partials for the combine kernel.
// Lane layout D[s-row=4*(lane>>4)+reg][q-col=lane&15]: softmax row in-lane + 2 shfl.
// Exact rel_shift semantics (incl. unmasked upper-triangle leak):
//   s<=t: (q[t]+bv).relk[T-1-(t-s)] | s==t+1: 0 | s>=t+2: (q[t+1]+bv).relk[s-t-2]
// 0.125 scale folded (exactly) into the bf16 q-fragments.
template<int NSPLIT>
__global__ __launch_bounds__(256, 4) void attn_kernel(
    const bf16_t* __restrict__ Q, const bf16_t* __restrict__ K,
    const bf16_t* __restrict__ VT, const bf16_t* __restrict__ RK,
    const float* __restrict__ bias_u, const float* __restrict__ bias_v,
    bf16_t* __restrict__ AO, float* __restrict__ PO, float* __restrict__ ML,
    int cpx)
{
    const int hw = blockIdx.x;
    const int logical = (hw & 7) * cpx + (hw >> 3);
    const int tile = logical & 31;
    int h, b, split;
    if (NSPLIT == 1) {
        split = 0; h = (logical >> 5) & 15; b = logical >> 9;
    } else {
        split = (logical >> 5) & 1; h = (logical >> 6) & 15; b = logical >> 10;
    }

    const int w = threadIdx.x >> 6, lane = threadIdx.x & 63;
    const int t0 = tile * 64;
    const int lr = lane & 15, lkg = lane >> 4;
    const int kd = lkg * 8;

    __shared__ float  pp[4][16][84];     // [wave][q(=lr)][window col]
    __shared__ bf16_t pl[4][16][72];     // [wave][q(=lr)][s offset]

    const int tb = t0 + w * 16;

    bf16x8 aqu[2], aqv[2], aqv2[2];
    {
        const int t  = tb + lr;
        const int t2 = (t + 1 < T_SEQ) ? t + 1 : T_SEQ - 1;
        const bf16_t* qp  = Q + ((size_t)(b*T_SEQ + t )*NH + h)*HD;
        const bf16_t* qp2 = Q + ((size_t)(b*T_SEQ + t2)*NH + h)*HD;
        const float* bu = bias_u + h*HD;
        const float* bv = bias_v + h*HD;
#pragma unroll
        for (int f = 0; f < 2; ++f) {
            const int k0 = f*32 + kd;
            bf16x8 q1 = *(const bf16x8*)(qp  + k0);
            bf16x8 q2 = *(const bf16x8*)(qp2 + k0);
#pragma unroll
            for (int j = 0; j < 8; ++j) {
                const float fu = bu[k0+j], fv = bv[k0+j];
                aqu [f][j] = (bf16_t)(((float)q1[j] + fu) * 0.125f);
                aqv [f][j] = (bf16_t)(((float)q1[j] + fv) * 0.125f);
                aqv2[f][j] = (bf16_t)(((float)q2[j] + fv) * 0.125f);
            }
        }
    }

    float m_run = -1e30f, l_run = 0.0f;   // per-lane stats for q = tb + lr
    f32x4 oacc[4];                        // rows q=4lkg+r, col d=16nf+lr
    f32x4 zf = {0.f, 0.f, 0.f, 0.f};
#pragma unroll
    for (int nf = 0; nf < 4; ++nf) oacc[nf] = zf;

    const bf16_t* Kb = K  + (size_t)(b*T_SEQ)*HID + h*HD;
    const bf16_t* Vb = VT + (size_t)((b*NH + h)*HD)*T_SEQ;
    const bf16_t* Rb = RK + h*HD;
    const int d15 = 15 - lr;
    const int sBeg = split * (T_SEQ / NSPLIT);

    for (int ss = 0; ss < T_SEQ / NSPLIT; ss += 64) {
        const int s0 = sBeg + ss;
        // ---- content scores: sc[j][r] = S[s=s0+16j+4lkg+r][q=tb+lr]
        f32x4 sc[4];
#pragma unroll
        for (int j = 0; j < 4; ++j) {
            const bf16_t* kp = Kb + (size_t)(s0 + j*16 + lr) * HID;
            bf16x8 a0 = *(const bf16x8*)(kp + kd);
            bf16x8 a1 = *(const bf16x8*)(kp + 32 + kd);
            sc[j] = mfma16(a1, aqu[1], mfma16(a0, aqu[0], zf));
        }

        // jwin = sof + d15, sof = 16j+4lkg+r in [0,63]
        // ---- branch 1 (s<=t): c1 = (s0-tb+T-16) + jwin
        if (s0 <= tb + 15) {
            const int base1 = s0 - tb + T_SEQ - 16;
#pragma unroll
            for (int jf = 0; jf < 5; ++jf) {
                const int c1 = base1 + jf*16 + lr;
                bf16x8 a0 = {}, a1 = {};
                if ((unsigned)c1 < (unsigned)T_SEQ) {
                    const bf16_t* rp = Rb + (size_t)c1 * HID;
                    a0 = *(const bf16x8*)(rp + kd);
                    a1 = *(const bf16x8*)(rp + 32 + kd);
                }
                f32x4 c = mfma16(a1, aqv[1], mfma16(a0, aqv[0], zf));
                *(f32x4*)&pp[w][lr][jf*16 + 4*lkg] = c;
            }
#pragma unroll
            for (int j = 0; j < 4; ++j)
#pragma unroll
                for (int r = 0; r < 4; ++r) {
                    const int sof = 16*j + 4*lkg + r;
                    const int dt  = (s0 + sof) - (tb + lr);
                    const float v = pp[w][lr][sof + d15];
                    sc[j][r] += (dt <= 0) ? v : 0.0f;
                }
        }
        // ---- branch 2 (s>=t+2, query row t+1): c2 = (s0-tb-17) + jwin
        if (s0 >= tb - 61) {
            const int base2 = s0 - tb - 17;
#pragma unroll
            for (int jf = 0; jf < 5; ++jf) {
                const int c2 = base2 + jf*16 + lr;
                bf16x8 a0 = {}, a1 = {};
                if ((unsigned)c2 < (unsigned)T_SEQ) {
                    const bf16_t* rp = Rb + (size_t)c2 * HID;
                    a0 = *(const bf16x8*)(rp + kd);
                    a1 = *(const bf16x8*)(rp + 32 + kd);
                }
                f32x4 c = mfma16(a1, aqv2[1], mfma16(a0, aqv2[0], zf));
                *(f32x4*)&pp[w][lr][jf*16 + 4*lkg] = c;
            }
#pragma unroll
            for (int j = 0; j < 4; ++j)
#pragma unroll
                for (int r = 0; r < 4; ++r) {
                    const int sof = 16*j + 4*lkg + r;
                    const int dt  = (s0 + sof) - (tb + lr);
                    const float v = pp[w][lr][sof + d15];
                    sc[j][r] += (dt >= 2) ? v : 0.0f;
                }
        }

        // ---- online softmax: row in-lane (16 vals) + 2 shfls
        float mx = fmaxf(fmaxf(fmaxf(sc[0][0], sc[0][1]), fmaxf(sc[0][2], sc[0][3])),
                         fmaxf(fmaxf(sc[1][0], sc[1][1]), fmaxf(sc[1][2], sc[1][3])));
        mx = fmaxf(mx, fmaxf(fmaxf(fmaxf(sc[2][0], sc[2][1]), fmaxf(sc[2][2], sc[2][3])),
                             fmaxf(fmaxf(sc[3][0], sc[3][1]), fmaxf(sc[3][2], sc[3][3]))));
        mx = fmaxf(mx, __shfl_xor(mx, 16, 64));
        mx = fmaxf(mx, __shfl_xor(mx, 32, 64));
        const float mnew = fmaxf(m_run, mx);
        const float fac = __expf(m_run - mnew);
        float sum = 0.0f;
#pragma unroll
        for (int j = 0; j < 4; ++j) {
            bf16x4 pk;
#pragma unroll
            for (int r = 0; r < 4; ++r) {
                const float p = __expf(sc[j][r] - mnew);
                sum += p;
                pk[r] = (bf16_t)p;
            }
            *(bf16x4*)&pl[w][lr][16*j + 4*lkg] = pk;
        }
        sum += __shfl_xor(sum, 16, 64);
        sum += __shfl_xor(sum, 32, 64);
        l_run = l_run * fac + sum;
        m_run = mnew;

#pragma unroll
        for (int r = 0; r < 4; ++r) {
            const float facq = __shfl(fac, 4*lkg + r, 64);
#pragma unroll
            for (int nf = 0; nf < 4; ++nf) oacc[nf][r] *= facq;
        }

        // ---- PV: O += P @ V
        bf16x8 pa0 = *(const bf16x8*)(&pl[w][lr][kd]);
        bf16x8 pa1 = *(const bf16x8*)(&pl[w][lr][32 + kd]);
#pragma unroll
        for (int nf = 0; nf < 4; ++nf) {
            const bf16_t* vp = Vb + (size_t)(nf*16 + lr) * T_SEQ + s0;
            bf16x8 b0 = *(const bf16x8*)(vp + kd);
            bf16x8 b1 = *(const bf16x8*)(vp + 32 + kd);
            oacc[nf] = mfma16(pa1, b1, mfma16(pa0, b0, oacc[nf]));
        }
    }

    if (NSPLIT == 1) {
        const float linv = 1.0f / l_run;
#pragma unroll
        for (int r = 0; r < 4; ++r) {
            const float lq = __shfl(linv, 4*lkg + r, 64);
            const int t = tb + 4*lkg + r;
#pragma unroll
            for (int nf = 0; nf < 4; ++nf)
                AO[(size_t)(b*T_SEQ + t)*HID + h*HD + nf*16 + lr] = (bf16_t)(oacc[nf][r] * lq);
        }
    } else {
        // partial store: unnormalized O (f32) + m,l
        float* po = PO + (((size_t)split*NB*NH + b*NH + h)*T_SEQ)*HD;
#pragma unroll
        for (int r = 0; r < 4; ++r)
#pragma unroll
            for (int nf = 0; nf < 4; ++nf)
                po[(size_t)(tb + 4*lkg + r)*HD + nf*16 + lr] = oacc[nf][r];
        if (lkg == 0) {
            float* ml = ML + ((size_t)split*NB*NH + b*NH + h)*2*T_SEQ;
            ml[tb + lr] = m_run;
            ml[T_SEQ + tb + lr] = l_run;
        }
    }
}

// Flash combine of the 2 KV-split partials -> AO bf16 [B,T,H*D].
__global__ __launch_bounds__(256) void combine_kernel(
    const float* __restrict__ PO, const float* __restrict__ ML,
    bf16_t* __restrict__ AO)
{
    const int idx = blockIdx.x * 256 + threadIdx.x;    // 65536 = B*H*T
    const int t = idx & (T_SEQ - 1);
    const int h = (idx >> 11) & (NH - 1);
    const int b = idx >> 15;
    const size_t poS = (size_t)NB*NH*T_SEQ*HD;
    const size_t mlS = (size_t)NB*NH*2*T_SEQ;
    const float* po1 = PO + (((size_t)b*NH + h)*T_SEQ + t)*HD;
    const float* po2 = po1 + poS;
    const float* ml1 = ML + ((size_t)b*NH + h)*2*T_SEQ;
    const float* ml2 = ml1 + mlS;
    const float m1 = ml1[t], l1 = ml1[T_SEQ + t];
    const float m2 = ml2[t], l2 = ml2[T_SEQ + t];
    const float M  = fmaxf(m1, m2);
    float f1 = __expf(m1 - M), f2 = __expf(m2 - M);
    const float linv = 1.0f / (f1*l1 + f2*l2);
    f1 *= linv; f2 *= linv;
    bf16_t* ao = AO + ((size_t)b*T_SEQ + t)*HID + h*HD;
#pragma unroll
    for (int d = 0; d < HD; d += 8) {
        f32x4 a0 = *(const f32x4*)(po1 + d), a1 = *(const f32x4*)(po1 + d + 4);
        f32x4 c0 = *(const f32x4*)(po2 + d), c1 = *(const f32x4*)(po2 + d + 4);
        bf16x8 o;
#pragma unroll
        for (int j = 0; j < 4; ++j) {
            o[j]     = (bf16_t)(f1*a0[j] + f2*c0[j]);
            o[4 + j] = (bf16_t)(f1*a1[j] + f2*c1[j]);
        }
        *(bf16x8*)(ao + d) = o;
    }
}

extern "C" void kernel_launch(void* const* d_in, const int* in_sizes, int n_in,
                              void* d_out, int out_size, void* d_ws, size_t ws_size,
                              hipStream_t stream) {
    const float* x    = (const float*)d_in[0];
    const float* pos  = (const float*)d_in[1];
    const float* Wq   = (const float*)d_in[2];
    const float* Wk   = (const float*)d_in[3];
    const float* Wv   = (const float*)d_in[4];
    const float* Wo   = (const float*)d_in[5];
    const float* Wrel = (const float*)d_in[6];
    const float* bu   = (const float*)d_in[7];
    const float* bv   = (const float*)d_in[8];

    // ws layout (bf16 elems): q 4M | k 4M | vT 4M | relk 2M | ab 4M  = 36 MiB,
    // then (if room) PO f32 partials 64 MiB + ML 1 MiB for KV-split.
    // xb (bf16 x) aliases ab: last read (V proj) precedes ab's first write.
    bf16_t* ws  = (bf16_t*)d_ws;
    const size_t M1 = 1024u * 1024u;
    bf16_t* qb  = ws;
    bf16_t* kb  = ws + 4*M1;
    bf16_t* vtb = ws + 8*M1;
    bf16_t* rkb = ws + 12*M1;
    bf16_t* ab  = ws + 14*M1;
    bf16_t* xb  = ab;

    const size_t baseBytes = 18*M1*2;
    const size_t poBytes = (size_t)2*NB*NH*T_SEQ*HD*4;
    const size_t mlBytes = (size_t)2*NB*NH*2*T_SEQ*4;
    float* PO = (float*)((char*)d_ws + baseBytes);
    float* ML = (float*)((char*)d_ws + baseBytes + poBytes);
    const bool split2 = ws_size >= baseBytes + poBytes + mlBytes;

    f32_to_bf16<<<2048, 256, 0, stream>>>(x, xb, 524288);

    gemm_xw<1,0><<<256, 256, 0, stream>>>(xb,  Wq,   qb,  4096, 32);
    gemm_xw<1,0><<<256, 256, 0, stream>>>(xb,  Wk,   kb,  4096, 32);
    gemm_xw<1,1><<<256, 256, 0, stream>>>(xb,  Wv,   vtb, 4096, 32);
    gemm_xw<0,0><<<128, 256, 0, stream>>>(pos, Wrel, rkb, 2048, 16);

    if (split2) {
        attn_kernel<2><<<2048, 256, 0, stream>>>(qb, kb, vtb, rkb, bu, bv, ab, PO, ML, 256);
        combine_kernel<<<256, 256, 0, stream>>>(PO, ML, ab);
    } else {
        attn_kernel<1><<<1024, 256, 0, stream>>>(qb, kb, vtb, rkb, bu, bv, ab, nullptr, nullptr, 128);
    }

    gemm_xw<1,2><<<256, 256, 0, stream>>>(ab, Wo, d_out, 4096, 32);
}

// Round 7
// 440.596 us; speedup vs baseline: 2.8344x; 2.8344x over previous
//
#include <hip/hip_runtime.h>
#include <hip/hip_bf16.h>

#define T_SEQ 2048
#define HID   1024
#define NH    16
#define HD    64
#define NB    2

typedef __bf16 bf16_t;
typedef bf16_t bf16x8 __attribute__((ext_vector_type(8)));
typedef bf16_t bf16x4 __attribute__((ext_vector_type(4)));
typedef float  f32x4  __attribute__((ext_vector_type(4)));

static __device__ __forceinline__ f32x4 mfma16(bf16x8 a, bf16x8 b, f32x4 c) {
    return __builtin_amdgcn_mfma_f32_16x16x32_bf16(a, b, c, 0, 0, 0);
}

// One-time f32 -> bf16 conversion (same round-to-nearest as in-register path).
__global__ __launch_bounds__(256) void f32_to_bf16(const float* __restrict__ in,
                                                   bf16_t* __restrict__ out, int n8) {
    const int i = blockIdx.x * 256 + threadIdx.x;
    if (i < n8) {
        const float4* p = (const float4*)(in + (size_t)i * 8);
        float4 a0 = p[0], a1 = p[1];
        bf16x8 v;
        v[0]=(bf16_t)a0.x; v[1]=(bf16_t)a0.y; v[2]=(bf16_t)a0.z; v[3]=(bf16_t)a0.w;
        v[4]=(bf16_t)a1.x; v[5]=(bf16_t)a1.y; v[6]=(bf16_t)a1.z; v[7]=(bf16_t)a1.w;
        *(bf16x8*)(out + (size_t)i * 8) = v;
    }
}

// C[M x 1024] = A[M x 1024] @ W^T, W row-major (torch Linear).
// AMODE 0: A f32 (convert in-register). AMODE 1: A bf16.
// OMODE 0: bf16 [M][1024]. OMODE 1: bf16 transposed to [B][H][D][T] (V). OMODE 2: f32.
template<int AMODE, int OMODE>
__global__ __launch_bounds__(256) void gemm_xw(const void* __restrict__ Av,
                                               const float* __restrict__ W,
                                               void* __restrict__ outv, int M, int cpx) {
    const int hw = blockIdx.x;
    const int logical = (hw & 7) * cpx + (hw >> 3);
    const int wid  = logical * 4 + (threadIdx.x >> 6);
    const int lane = threadIdx.x & 63;
    const int mt = wid / 16, nt = wid % 16;
    const int row0 = mt * 64, col0 = nt * 64;
    const int lr = lane & 15;
    const int kd = (lane >> 4) * 8;

    f32x4 acc[4][4] = {};

    for (int k = 0; k < HID; k += 32) {
        bf16x8 af[4], bq[4];
#pragma unroll
        for (int i = 0; i < 4; ++i) {
            if (AMODE == 0) {
                const float* ap = (const float*)Av + (size_t)(row0 + i*16 + lr) * HID + k + kd;
                float4 a0 = *(const float4*)ap;
                float4 a1 = *(const float4*)(ap + 4);
                af[i][0]=(bf16_t)a0.x; af[i][1]=(bf16_t)a0.y; af[i][2]=(bf16_t)a0.z; af[i][3]=(bf16_t)a0.w;
                af[i][4]=(bf16_t)a1.x; af[i][5]=(bf16_t)a1.y; af[i][6]=(bf16_t)a1.z; af[i][7]=(bf16_t)a1.w;
            } else {
                af[i] = *(const bf16x8*)((const bf16_t*)Av + (size_t)(row0 + i*16 + lr) * HID + k + kd);
            }
        }
#pragma unroll
        for (int j = 0; j < 4; ++j) {
            const float* wp = W + (size_t)(col0 + j*16 + lr) * HID + k + kd;
            float4 b0 = *(const float4*)wp;
            float4 b1 = *(const float4*)(wp + 4);
            bq[j][0]=(bf16_t)b0.x; bq[j][1]=(bf16_t)b0.y; bq[j][2]=(bf16_t)b0.z; bq[j][3]=(bf16_t)b0.w;
            bq[j][4]=(bf16_t)b1.x; bq[j][5]=(bf16_t)b1.y; bq[j][6]=(bf16_t)b1.z; bq[j][7]=(bf16_t)b1.w;
        }
#pragma unroll
        for (int i = 0; i < 4; ++i)
#pragma unroll
            for (int j = 0; j < 4; ++j)
                acc[i][j] = mfma16(af[i], bq[j], acc[i][j]);
    }

    const int rb = (lane >> 4) * 4;
#pragma unroll
    for (int i = 0; i < 4; ++i) {
#pragma unroll
        for (int j = 0; j < 4; ++j) {
            const int col = col0 + j*16 + lr;
            if (OMODE == 0) {
                bf16_t* ob = (bf16_t*)outv;
#pragma unroll
                for (int r = 0; r < 4; ++r)
                    ob[(size_t)(row0 + i*16 + rb + r) * HID + col] = (bf16_t)acc[i][j][r];
            } else if (OMODE == 1) {
                const int row = row0 + i*16 + rb;
                const int bb = row >> 11, t = row & (T_SEQ - 1);
                const int hh = col >> 6,  d = col & 63;
                bf16x4 pk;
#pragma unroll
                for (int r = 0; r < 4; ++r) pk[r] = (bf16_t)acc[i][j][r];
                *(bf16x4*)((bf16_t*)outv + ((size_t)((bb*NH + hh)*HD + d))*T_SEQ + t) = pk;
            } else {
                float* of = (float*)outv;
#pragma unroll
                for (int r = 0; r < 4; ++r)
                    of[(size_t)(row0 + i*16 + rb + r) * HID + col] = acc[i][j][r];
            }
        }
    }
}

// Fused rel-shift attention, SWAPPED orientation + block-level LDS staging.
// Round-6 finding: per-lane fragment loads (lane stride 2-4KB) made every
// global_load touch 32-64 cache lines -> L1/TA transaction-bound (~15k cy per
// wave-tile, all pipes idle). Fix: 4 waves cooperatively stage K/V tiles and
// the two 128-row rel-k windows into LDS with lane-CONTIGUOUS loads
// (16 lines/instr), XOR-swizzled (colE ^ ((row&7)<<3)) so stride-128B
// fragment ds_reads are conflict-free. Two uniform __syncthreads per tile.
// Lane layout D[s-row=4*(lane>>4)+reg][q-col=lane&15]: softmax row in-lane + 2 shfl.
// Exact rel_shift semantics (incl. unmasked upper-triangle leak):
//   s<=t: (q[t]+bv).relk[T-1-(t-s)] | s==t+1: 0 | s>=t+2: (q[t+1]+bv).relk[s-t-2]
// 0.125 scale folded (exactly) into the bf16 q-fragments.
template<int NSPLIT>
__global__ __launch_bounds__(256) void attn_kernel(
    const bf16_t* __restrict__ Q, const bf16_t* __restrict__ K,
    const bf16_t* __restrict__ VT, const bf16_t* __restrict__ RK,
    const float* __restrict__ bias_u, const float* __restrict__ bias_v,
    bf16_t* __restrict__ AO, float* __restrict__ PO, float* __restrict__ ML,
    int cpx)
{
    const int hw = blockIdx.x;
    const int logical = (hw & 7) * cpx + (hw >> 3);
    const int tile = logical & 31;
    int h, b, split;
    if (NSPLIT == 1) {
        split = 0; h = (logical >> 5) & 15; b = logical >> 9;
    } else {
        split = (logical >> 5) & 1; h = (logical >> 6) & 15; b = logical >> 10;
    }

    const int w = threadIdx.x >> 6, lane = threadIdx.x & 63;
    const int t0 = tile * 64;
    const int lr = lane & 15, lkg = lane >> 4;
    const int kd = lkg * 8;

    __shared__ bf16_t Kl[64*64];         // K tile  [s_off 64][d 64], swizzled
    __shared__ bf16_t Vl[64*64];         // V^T tile[d 64][t_off 64], swizzled
    __shared__ bf16_t R1l[128*64];       // rel-k window branch1, swizzled, OOB=0
    __shared__ bf16_t R2l[128*64];       // rel-k window branch2, swizzled, OOB=0
    __shared__ float  pp[4][16][84];     // [wave][q(=lr)][window col]
    __shared__ bf16_t pl[4][16][72];     // [wave][q(=lr)][s offset]

    const int tb = t0 + w * 16;

    bf16x8 aqu[2], aqv[2], aqv2[2];
    {
        const int t  = tb + lr;
        const int t2 = (t + 1 < T_SEQ) ? t + 1 : T_SEQ - 1;
        const bf16_t* qp  = Q + ((size_t)(b*T_SEQ + t )*NH + h)*HD;
        const bf16_t* qp2 = Q + ((size_t)(b*T_SEQ + t2)*NH + h)*HD;
        const float* bu = bias_u + h*HD;
        const float* bv = bias_v + h*HD;
#pragma unroll
        for (int f = 0; f < 2; ++f) {
            const int k0 = f*32 + kd;
            bf16x8 q1 = *(const bf16x8*)(qp  + k0);
            bf16x8 q2 = *(const bf16x8*)(qp2 + k0);
#pragma unroll
            for (int j = 0; j < 8; ++j) {
                const float fu = bu[k0+j], fv = bv[k0+j];
                aqu [f][j] = (bf16_t)(((float)q1[j] + fu) * 0.125f);
                aqv [f][j] = (bf16_t)(((float)q1[j] + fv) * 0.125f);
                aqv2[f][j] = (bf16_t)(((float)q2[j] + fv) * 0.125f);
            }
        }
    }

    float m_run = -1e30f, l_run = 0.0f;   // per-lane stats for q = tb + lr
    f32x4 oacc[4];                        // rows q=4lkg+r, col d=16nf+lr
    f32x4 zf = {0.f, 0.f, 0.f, 0.f};
#pragma unroll
    for (int nf = 0; nf < 4; ++nf) oacc[nf] = zf;

    const bf16_t* Kb = K  + (size_t)(b*T_SEQ)*HID + h*HD;
    const bf16_t* Vb = VT + (size_t)((b*NH + h)*HD)*T_SEQ;
    const bf16_t* Rb = RK + h*HD;
    const int d15 = 15 - lr;
    const int sBeg = split * (T_SEQ / NSPLIT);

    for (int ss = 0; ss < T_SEQ / NSPLIT; ss += 64) {
        const int s0 = sBeg + ss;
        const int r1base = s0 - t0 + T_SEQ - 64;   // branch1 window start (global row)
        const int r2base = s0 - t0 - 65;           // branch2 window start
        const bool anyB1 = (s0 <= t0 + 63);        // block-uniform triggers
        const bool anyB2 = (s0 >= t0 - 61);

        // ---- STAGE (coalesced: 8 lanes cover one 128B row) ----
#pragma unroll
        for (int i = 0; i < 2; ++i) {
            const int e = (2*w + i)*512 + lane*8;
            const int row = e >> 6, colE = e & 63;
            const int dstE = row*64 + (colE ^ ((row & 7) << 3));
            *(bf16x8*)&Kl[dstE] = *(const bf16x8*)(Kb + (size_t)(s0 + row)*HID + colE);
            *(bf16x8*)&Vl[dstE] = *(const bf16x8*)(Vb + (size_t)row*T_SEQ + s0 + colE);
        }
        if (anyB1) {
#pragma unroll
            for (int i = 0; i < 4; ++i) {
                const int e = (4*w + i)*512 + lane*8;
                const int row = e >> 6, colE = e & 63;
                const int g = r1base + row;
                bf16x8 v = {};
                if ((unsigned)g < (unsigned)T_SEQ)
                    v = *(const bf16x8*)(Rb + (size_t)g*HID + colE);
                *(bf16x8*)&R1l[row*64 + (colE ^ ((row & 7) << 3))] = v;
            }
        }
        if (anyB2) {
#pragma unroll
            for (int i = 0; i < 4; ++i) {
                const int e = (4*w + i)*512 + lane*8;
                const int row = e >> 6, colE = e & 63;
                const int g = r2base + row;
                bf16x8 v = {};
                if ((unsigned)g < (unsigned)T_SEQ)
                    v = *(const bf16x8*)(Rb + (size_t)g*HID + colE);
                *(bf16x8*)&R2l[row*64 + (colE ^ ((row & 7) << 3))] = v;
            }
        }
        __syncthreads();

        // ---- content scores: sc[j][r] = S[s=s0+16j+4lkg+r][q=tb+lr]
        f32x4 sc[4];
#pragma unroll
        for (int j = 0; j < 4; ++j) {
            const int row = j*16 + lr;
            const int sw = (row & 7) << 3;
            bf16x8 a0 = *(const bf16x8*)&Kl[row*64 + (kd ^ sw)];
            bf16x8 a1 = *(const bf16x8*)&Kl[row*64 + ((32 + kd) ^ sw)];
            sc[j] = mfma16(a1, aqu[1], mfma16(a0, aqu[0], zf));
        }

        // jwin = sof + d15, sof = 16j+4lkg+r in [0,63]
        // ---- branch 1 (s<=t): per-wave window rows rr = 48-16w+jf*16+lr
        if (s0 <= tb + 15) {
#pragma unroll
            for (int jf = 0; jf < 5; ++jf) {
                const int rr = 48 - 16*w + jf*16 + lr;
                const int sw = (rr & 7) << 3;
                bf16x8 a0 = *(const bf16x8*)&R1l[rr*64 + (kd ^ sw)];
                bf16x8 a1 = *(const bf16x8*)&R1l[rr*64 + ((32 + kd) ^ sw)];
                f32x4 c = mfma16(a1, aqv[1], mfma16(a0, aqv[0], zf));
                *(f32x4*)&pp[w][lr][jf*16 + 4*lkg] = c;
            }
#pragma unroll
            for (int j = 0; j < 4; ++j)
#pragma unroll
                for (int r = 0; r < 4; ++r) {
                    const int sof = 16*j + 4*lkg + r;
                    const int dt  = (s0 + sof) - (tb + lr);
                    const float v = pp[w][lr][sof + d15];
                    sc[j][r] += (dt <= 0) ? v : 0.0f;
                }
        }
        // ---- branch 2 (s>=t+2, query row t+1)
        if (s0 >= tb - 61) {
#pragma unroll
            for (int jf = 0; jf < 5; ++jf) {
                const int rr = 48 - 16*w + jf*16 + lr;
                const int sw = (rr & 7) << 3;
                bf16x8 a0 = *(const bf16x8*)&R2l[rr*64 + (kd ^ sw)];
                bf16x8 a1 = *(const bf16x8*)&R2l[rr*64 + ((32 + kd) ^ sw)];
                f32x4 c = mfma16(a1, aqv2[1], mfma16(a0, aqv2[0], zf));
                *(f32x4*)&pp[w][lr][jf*16 + 4*lkg] = c;
            }
#pragma unroll
            for (int j = 0; j < 4; ++j)
#pragma unroll
                for (int r = 0; r < 4; ++r) {
                    const int sof = 16*j + 4*lkg + r;
                    const int dt  = (s0 + sof) - (tb + lr);
                    const float v = pp[w][lr][sof + d15];
                    sc[j][r] += (dt >= 2) ? v : 0.0f;
                }
        }

        // ---- online softmax: row in-lane (16 vals) + 2 shfls
        float mx = fmaxf(fmaxf(fmaxf(sc[0][0], sc[0][1]), fmaxf(sc[0][2], sc[0][3])),
                         fmaxf(fmaxf(sc[1][0], sc[1][1]), fmaxf(sc[1][2], sc[1][3])));
        mx = fmaxf(mx, fmaxf(fmaxf(fmaxf(sc[2][0], sc[2][1]), fmaxf(sc[2][2], sc[2][3])),
                             fmaxf(fmaxf(sc[3][0], sc[3][1]), fmaxf(sc[3][2], sc[3][3]))));
        mx = fmaxf(mx, __shfl_xor(mx, 16, 64));
        mx = fmaxf(mx, __shfl_xor(mx, 32, 64));
        const float mnew = fmaxf(m_run, mx);
        const float fac = __expf(m_run - mnew);
        float sum = 0.0f;
#pragma unroll
        for (int j = 0; j < 4; ++j) {
            bf16x4 pk;
#pragma unroll
            for (int r = 0; r < 4; ++r) {
                const float p = __expf(sc[j][r] - mnew);
                sum += p;
                pk[r] = (bf16_t)p;
            }
            *(bf16x4*)&pl[w][lr][16*j + 4*lkg] = pk;
        }
        sum += __shfl_xor(sum, 16, 64);
        sum += __shfl_xor(sum, 32, 64);
        l_run = l_run * fac + sum;
        m_run = mnew;

#pragma unroll
        for (int r = 0; r < 4; ++r) {
            const float facq = __shfl(fac, 4*lkg + r, 64);
#pragma unroll
            for (int nf = 0; nf < 4; ++nf) oacc[nf][r] *= facq;
        }

        // ---- PV: O += P @ V (V frags from swizzled LDS)
        bf16x8 pa0 = *(const bf16x8*)(&pl[w][lr][kd]);
        bf16x8 pa1 = *(const bf16x8*)(&pl[w][lr][32 + kd]);
#pragma unroll
        for (int nf = 0; nf < 4; ++nf) {
            const int row = nf*16 + lr;
            const int sw = (row & 7) << 3;
            bf16x8 b0 = *(const bf16x8*)&Vl[row*64 + (kd ^ sw)];
            bf16x8 b1 = *(const bf16x8*)&Vl[row*64 + ((32 + kd) ^ sw)];
            oacc[nf] = mfma16(pa1, b1, mfma16(pa0, b0, oacc[nf]));
        }
        __syncthreads();   // LDS tiles free for next iteration's stage
    }

    if (NSPLIT == 1) {
        const float linv = 1.0f / l_run;
#pragma unroll
        for (int r = 0; r < 4; ++r) {
            const float lq = __shfl(linv, 4*lkg + r, 64);
            const int t = tb + 4*lkg + r;
#pragma unroll
            for (int nf = 0; nf < 4; ++nf)
                AO[(size_t)(b*T_SEQ + t)*HID + h*HD + nf*16 + lr] = (bf16_t)(oacc[nf][r] * lq);
        }
    } else {
        // partial store: unnormalized O (f32) + m,l
        float* po = PO + (((size_t)split*NB*NH + b*NH + h)*T_SEQ)*HD;
#pragma unroll
        for (int r = 0; r < 4; ++r)
#pragma unroll
            for (int nf = 0; nf < 4; ++nf)
                po[(size_t)(tb + 4*lkg + r)*HD + nf*16 + lr] = oacc[nf][r];
        if (lkg == 0) {
            float* ml = ML + ((size_t)split*NB*NH + b*NH + h)*2*T_SEQ;
            ml[tb + lr] = m_run;
            ml[T_SEQ + tb + lr] = l_run;
        }
    }
}

// Flash combine of the 2 KV-split partials -> AO bf16 [B,T,H*D].
__global__ __launch_bounds__(256) void combine_kernel(
    const float* __restrict__ PO, const float* __restrict__ ML,
    bf16_t* __restrict__ AO)
{
    const int idx = blockIdx.x * 256 + threadIdx.x;    // 65536 = B*H*T
    const int t = idx & (T_SEQ - 1);
    const int h = (idx >> 11) & (NH - 1);
    const int b = idx >> 15;
    const size_t poS = (size_t)NB*NH*T_SEQ*HD;
    const size_t mlS = (size_t)NB*NH*2*T_SEQ;
    const float* po1 = PO + (((size_t)b*NH + h)*T_SEQ + t)*HD;
    const float* po2 = po1 + poS;
    const float* ml1 = ML + ((size_t)b*NH + h)*2*T_SEQ;
    const float* ml2 = ml1 + mlS;
    const float m1 = ml1[t], l1 = ml1[T_SEQ + t];
    const float m2 = ml2[t], l2 = ml2[T_SEQ + t];
    const float M  = fmaxf(m1, m2);
    float f1 = __expf(m1 - M), f2 = __expf(m2 - M);
    const float linv = 1.0f / (f1*l1 + f2*l2);
    f1 *= linv; f2 *= linv;
    bf16_t* ao = AO + ((size_t)b*T_SEQ + t)*HID + h*HD;
#pragma unroll
    for (int d = 0; d < HD; d += 8) {
        f32x4 a0 = *(const f32x4*)(po1 + d), a1 = *(const f32x4*)(po1 + d + 4);
        f32x4 c0 = *(const f32x4*)(po2 + d), c1 = *(const f32x4*)(po2 + d + 4);
        bf16x8 o;
#pragma unroll
        for (int j = 0; j < 4; ++j) {
            o[j]     = (bf16_t)(f1*a0[j] + f2*c0[j]);
            o[4 + j] = (bf16_t)(f1*a1[j] + f2*c1[j]);
        }
        *(bf16x8*)(ao + d) = o;
    }
}

extern "C" void kernel_launch(void* const* d_in, const int* in_sizes, int n_in,
                              void* d_out, int out_size, void* d_ws, size_t ws_size,
                              hipStream_t stream) {
    const float* x    = (const float*)d_in[0];
    const float* pos  = (const float*)d_in[1];
    const float* Wq   = (const float*)d_in[2];
    const float* Wk   = (const float*)d_in[3];
    const float* Wv   = (const float*)d_in[4];
    const float* Wo   = (const float*)d_in[5];
    const float* Wrel = (const float*)d_in[6];
    const float* bu   = (const float*)d_in[7];
    const float* bv   = (const float*)d_in[8];

    // ws layout (bf16 elems): q 4M | k 4M | vT 4M | relk 2M | ab 4M  = 36 MiB,
    // then (if room) PO f32 partials 64 MiB + ML 1 MiB for KV-split.
    // xb (bf16 x) aliases ab: last read (V proj) precedes ab's first write.
    bf16_t* ws  = (bf16_t*)d_ws;
    const size_t M1 = 1024u * 1024u;
    bf16_t* qb  = ws;
    bf16_t* kb  = ws + 4*M1;
    bf16_t* vtb = ws + 8*M1;
    bf16_t* rkb = ws + 12*M1;
    bf16_t* ab  = ws + 14*M1;
    bf16_t* xb  = ab;

    const size_t baseBytes = 18*M1*2;
    const size_t poBytes = (size_t)2*NB*NH*T_SEQ*HD*4;
    const size_t mlBytes = (size_t)2*NB*NH*2*T_SEQ*4;
    float* PO = (float*)((char*)d_ws + baseBytes);
    float* ML = (float*)((char*)d_ws + baseBytes + poBytes);
    const bool split2 = ws_size >= baseBytes + poBytes + mlBytes;

    f32_to_bf16<<<2048, 256, 0, stream>>>(x, xb, 524288);

    gemm_xw<1,0><<<256, 256, 0, stream>>>(xb,  Wq,   qb,  4096, 32);
    gemm_xw<1,0><<<256, 256, 0, stream>>>(xb,  Wk,   kb,  4096, 32);
    gemm_xw<1,1><<<256, 256, 0, stream>>>(xb,  Wv,   vtb, 4096, 32);
    gemm_xw<0,0><<<128, 256, 0, stream>>>(pos, Wrel, rkb, 2048, 16);

    if (split2) {
        attn_kernel<2><<<2048, 256, 0, stream>>>(qb, kb, vtb, rkb, bu, bv, ab, PO, ML, 256);
        combine_kernel<<<256, 256, 0, stream>>>(PO, ML, ab);
    } else {
        attn_kernel<1><<<1024, 256, 0, stream>>>(qb, kb, vtb, rkb, bu, bv, ab, nullptr, nullptr, 128);
    }

    gemm_xw<1,2><<<256, 256, 0, stream>>>(ab, Wo, d_out, 4096, 32);
}

// Round 8
// 296.902 us; speedup vs baseline: 4.2062x; 1.4840x over previous
//
#include <hip/hip_runtime.h>
#include <hip/hip_bf16.h>

#define T_SEQ 2048
#define HID   1024
#define NH    16
#define HD    64
#define NB    2

typedef __bf16 bf16_t;
typedef bf16_t bf16x8 __attribute__((ext_vector_type(8)));
typedef bf16_t bf16x4 __attribute__((ext_vector_type(4)));
typedef float  f32x4  __attribute__((ext_vector_type(4)));

static __device__ __forceinline__ f32x4 mfma16(bf16x8 a, bf16x8 b, f32x4 c) {
    return __builtin_amdgcn_mfma_f32_16x16x32_bf16(a, b, c, 0, 0, 0);
}

// One-pass f32 -> bf16 conversion of x, pos, and all 5 weights (same RTN cast
// as the old in-register convert -> bit-identical downstream numerics).
// Region block counts: x 2048 | pos 1024 | each W 512. Grid = 5632.
__global__ __launch_bounds__(256) void cvt_all(
    const float* __restrict__ x, const float* __restrict__ pos,
    const float* __restrict__ wq, const float* __restrict__ wk,
    const float* __restrict__ wv, const float* __restrict__ wo,
    const float* __restrict__ wrel,
    bf16_t* __restrict__ xb, bf16_t* __restrict__ pb,
    bf16_t* __restrict__ wqb, bf16_t* __restrict__ wkb,
    bf16_t* __restrict__ wvb, bf16_t* __restrict__ wob,
    bf16_t* __restrict__ wrelb)
{
    int blk = blockIdx.x;
    const float* in; bf16_t* out;
    if (blk < 2048)      { in = x;   out = xb; }
    else if (blk < 3072) { in = pos; out = pb; blk -= 2048; }
    else {
        const int wi = (blk - 3072) >> 9; blk = (blk - 3072) & 511;
        switch (wi) {
            case 0:  in = wq;   out = wqb;   break;
            case 1:  in = wk;   out = wkb;   break;
            case 2:  in = wv;   out = wvb;   break;
            case 3:  in = wo;   out = wob;   break;
            default: in = wrel; out = wrelb; break;
        }
    }
    const int i = blk * 256 + threadIdx.x;
    const float4* p = (const float4*)(in + (size_t)i * 8);
    float4 a0 = p[0], a1 = p[1];
    bf16x8 v;
    v[0]=(bf16_t)a0.x; v[1]=(bf16_t)a0.y; v[2]=(bf16_t)a0.z; v[3]=(bf16_t)a0.w;
    v[4]=(bf16_t)a1.x; v[5]=(bf16_t)a1.y; v[6]=(bf16_t)a1.z; v[7]=(bf16_t)a1.w;
    *(bf16x8*)(out + (size_t)i * 8) = v;
}

// C[M x 1024] = A[M x 1024] @ W^T, A and W both bf16, W [1024 x 1024] row-major.
// 128x128 tile, BK=64, 4 waves in 2x2 quadrants (64x64 each), cooperative
// coalesced staging (1KB/instr = minimal 16 cache lines) into XOR-swizzled LDS
// (colE ^ ((row&7)<<3); stride-128B ds_read_b128 then max 2-way = free), with
// reg-prefetch of tile t+1 during compute of tile t.
// K-accumulation order identical to rounds 1-7 -> bit-identical output.
// OMODE 0: bf16 [M][1024]. OMODE 1: bf16 transposed to [B][H][D][T] (V). OMODE 2: f32.
template<int OMODE>
__global__ __launch_bounds__(256) void gemm_bb(const bf16_t* __restrict__ A,
                                               const bf16_t* __restrict__ W,
                                               void* __restrict__ outv, int M, int cpx) {
    const int hw = blockIdx.x;
    const int logical = (hw & 7) * cpx + (hw >> 3);
    const int mt = logical >> 3, nt = logical & 7;
    const int row0 = mt * 128, col0 = nt * 128;
    const int tid = threadIdx.x;
    const int w = tid >> 6, lane = tid & 63;
    const int wr = (w >> 1) * 64, wc = (w & 1) * 64;
    const int lr = lane & 15, lkg = lane >> 4;
    const int kd = lkg * 8;

    __shared__ bf16_t Al[128*64];    // 16 KB, swizzled
    __shared__ bf16_t Bl[128*64];    // 16 KB, swizzled

    const int sRow = tid >> 3;              // 0..31, rows sRow + 32*i
    const int sCol = (tid & 7) * 8;         // 16B chunk within 128B row

    f32x4 acc[4][4] = {};
    bf16x8 sa[4], sb[4];

    // prologue: stage tile 0
#pragma unroll
    for (int i = 0; i < 4; ++i) {
        const int r = sRow + 32*i;
        sa[i] = *(const bf16x8*)(A + (size_t)(row0 + r)*HID + sCol);
        sb[i] = *(const bf16x8*)(W + (size_t)(col0 + r)*HID + sCol);
    }
#pragma unroll
    for (int i = 0; i < 4; ++i) {
        const int r = sRow + 32*i;
        const int dst = r*64 + (sCol ^ ((r & 7) << 3));
        *(bf16x8*)&Al[dst] = sa[i];
        *(bf16x8*)&Bl[dst] = sb[i];
    }
    __syncthreads();

    for (int t = 0; t < 16; ++t) {
        if (t < 15) {
            const int k0 = (t + 1) * 64;
#pragma unroll
            for (int i = 0; i < 4; ++i) {
                const int r = sRow + 32*i;
                sa[i] = *(const bf16x8*)(A + (size_t)(row0 + r)*HID + k0 + sCol);
                sb[i] = *(const bf16x8*)(W + (size_t)(col0 + r)*HID + k0 + sCol);
            }
        }
#pragma unroll
        for (int ks = 0; ks < 2; ++ks) {
            bf16x8 af[4], bq[4];
#pragma unroll
            for (int i = 0; i < 4; ++i) {
                const int ar = wr + i*16 + lr;
                af[i] = *(const bf16x8*)&Al[ar*64 + ((ks*32 + kd) ^ ((ar & 7) << 3))];
                const int br = wc + i*16 + lr;
                bq[i] = *(const bf16x8*)&Bl[br*64 + ((ks*32 + kd) ^ ((br & 7) << 3))];
            }
#pragma unroll
            for (int i = 0; i < 4; ++i)
#pragma unroll
                for (int j = 0; j < 4; ++j)
                    acc[i][j] = mfma16(af[i], bq[j], acc[i][j]);
        }
        __syncthreads();
        if (t < 15) {
#pragma unroll
            for (int i = 0; i < 4; ++i) {
                const int r = sRow + 32*i;
                const int dst = r*64 + (sCol ^ ((r & 7) << 3));
                *(bf16x8*)&Al[dst] = sa[i];
                *(bf16x8*)&Bl[dst] = sb[i];
            }
            __syncthreads();
        }
    }

    const int rb = lkg * 4;
#pragma unroll
    for (int i = 0; i < 4; ++i) {
#pragma unroll
        for (int j = 0; j < 4; ++j) {
            const int col = col0 + wc + j*16 + lr;
            const int row = row0 + wr + i*16 + rb;
            if (OMODE == 0) {
                bf16_t* ob = (bf16_t*)outv;
#pragma unroll
                for (int r = 0; r < 4; ++r)
                    ob[(size_t)(row + r) * HID + col] = (bf16_t)acc[i][j][r];
            } else if (OMODE == 1) {
                const int bb = row >> 11, tt = row & (T_SEQ - 1);
                const int hh = col >> 6,  d = col & 63;
                bf16x4 pk;
#pragma unroll
                for (int r = 0; r < 4; ++r) pk[r] = (bf16_t)acc[i][j][r];
                *(bf16x4*)((bf16_t*)outv + ((size_t)((bb*NH + hh)*HD + d))*T_SEQ + tt) = pk;
            } else {
                float* of = (float*)outv;
#pragma unroll
                for (int r = 0; r < 4; ++r)
                    of[(size_t)(row + r) * HID + col] = acc[i][j][r];
            }
        }
    }
}

// Fused rel-shift attention, SWAPPED orientation + block-level LDS staging
// (unchanged from round 7: coalesced cooperative staging, XOR swizzle,
// in-lane softmax, exact rel_shift semantics, 0.125 folded into q-frags).
template<int NSPLIT>
__global__ __launch_bounds__(256) void attn_kernel(
    const bf16_t* __restrict__ Q, const bf16_t* __restrict__ K,
    const bf16_t* __restrict__ VT, const bf16_t* __restrict__ RK,
    const float* __restrict__ bias_u, const float* __restrict__ bias_v,
    bf16_t* __restrict__ AO, float* __restrict__ PO, float* __restrict__ ML,
    int cpx)
{
    const int hw = blockIdx.x;
    const int logical = (hw & 7) * cpx + (hw >> 3);
    const int tile = logical & 31;
    int h, b, split;
    if (NSPLIT == 1) {
        split = 0; h = (logical >> 5) & 15; b = logical >> 9;
    } else {
        split = (logical >> 5) & 1; h = (logical >> 6) & 15; b = logical >> 10;
    }

    const int w = threadIdx.x >> 6, lane = threadIdx.x & 63;
    const int t0 = tile * 64;
    const int lr = lane & 15, lkg = lane >> 4;
    const int kd = lkg * 8;

    __shared__ bf16_t Kl[64*64];
    __shared__ bf16_t Vl[64*64];
    __shared__ bf16_t R1l[128*64];
    __shared__ bf16_t R2l[128*64];
    __shared__ float  pp[4][16][84];
    __shared__ bf16_t pl[4][16][72];

    const int tb = t0 + w * 16;

    bf16x8 aqu[2], aqv[2], aqv2[2];
    {
        const int t  = tb + lr;
        const int t2 = (t + 1 < T_SEQ) ? t + 1 : T_SEQ - 1;
        const bf16_t* qp  = Q + ((size_t)(b*T_SEQ + t )*NH + h)*HD;
        const bf16_t* qp2 = Q + ((size_t)(b*T_SEQ + t2)*NH + h)*HD;
        const float* bu = bias_u + h*HD;
        const float* bv = bias_v + h*HD;
#pragma unroll
        for (int f = 0; f < 2; ++f) {
            const int k0 = f*32 + kd;
            bf16x8 q1 = *(const bf16x8*)(qp  + k0);
            bf16x8 q2 = *(const bf16x8*)(qp2 + k0);
#pragma unroll
            for (int j = 0; j < 8; ++j) {
                const float fu = bu[k0+j], fv = bv[k0+j];
                aqu [f][j] = (bf16_t)(((float)q1[j] + fu) * 0.125f);
                aqv [f][j] = (bf16_t)(((float)q1[j] + fv) * 0.125f);
                aqv2[f][j] = (bf16_t)(((float)q2[j] + fv) * 0.125f);
            }
        }
    }

    float m_run = -1e30f, l_run = 0.0f;
    f32x4 oacc[4];
    f32x4 zf = {0.f, 0.f, 0.f, 0.f};
#pragma unroll
    for (int nf = 0; nf < 4; ++nf) oacc[nf] = zf;

    const bf16_t* Kb = K  + (size_t)(b*T_SEQ)*HID + h*HD;
    const bf16_t* Vb = VT + (size_t)((b*NH + h)*HD)*T_SEQ;
    const bf16_t* Rb = RK + h*HD;
    const int d15 = 15 - lr;
    const int sBeg = split * (T_SEQ / NSPLIT);

    for (int ss = 0; ss < T_SEQ / NSPLIT; ss += 64) {
        const int s0 = sBeg + ss;
        const int r1base = s0 - t0 + T_SEQ - 64;
        const int r2base = s0 - t0 - 65;
        const bool anyB1 = (s0 <= t0 + 63);
        const bool anyB2 = (s0 >= t0 - 61);

        // ---- STAGE (coalesced: 8 lanes cover one 128B row) ----
#pragma unroll
        for (int i = 0; i < 2; ++i) {
            const int e = (2*w + i)*512 + lane*8;
            const int row = e >> 6, colE = e & 63;
            const int dstE = row*64 + (colE ^ ((row & 7) << 3));
            *(bf16x8*)&Kl[dstE] = *(const bf16x8*)(Kb + (size_t)(s0 + row)*HID + colE);
            *(bf16x8*)&Vl[dstE] = *(const bf16x8*)(Vb + (size_t)row*T_SEQ + s0 + colE);
        }
        if (anyB1) {
#pragma unroll
            for (int i = 0; i < 4; ++i) {
                const int e = (4*w + i)*512 + lane*8;
                const int row = e >> 6, colE = e & 63;
                const int g = r1base + row;
                bf16x8 v = {};
                if ((unsigned)g < (unsigned)T_SEQ)
                    v = *(const bf16x8*)(Rb + (size_t)g*HID + colE);
                *(bf16x8*)&R1l[row*64 + (colE ^ ((row & 7) << 3))] = v;
            }
        }
        if (anyB2) {
#pragma unroll
            for (int i = 0; i < 4; ++i) {
                const int e = (4*w + i)*512 + lane*8;
                const int row = e >> 6, colE = e & 63;
                const int g = r2base + row;
                bf16x8 v = {};
                if ((unsigned)g < (unsigned)T_SEQ)
                    v = *(const bf16x8*)(Rb + (size_t)g*HID + colE);
                *(bf16x8*)&R2l[row*64 + (colE ^ ((row & 7) << 3))] = v;
            }
        }
        __syncthreads();

        f32x4 sc[4];
#pragma unroll
        for (int j = 0; j < 4; ++j) {
            const int row = j*16 + lr;
            const int sw = (row & 7) << 3;
            bf16x8 a0 = *(const bf16x8*)&Kl[row*64 + (kd ^ sw)];
            bf16x8 a1 = *(const bf16x8*)&Kl[row*64 + ((32 + kd) ^ sw)];
            sc[j] = mfma16(a1, aqu[1], mfma16(a0, aqu[0], zf));
        }

        if (s0 <= tb + 15) {
#pragma unroll
            for (int jf = 0; jf < 5; ++jf) {
                const int rr = 48 - 16*w + jf*16 + lr;
                const int sw = (rr & 7) << 3;
                bf16x8 a0 = *(const bf16x8*)&R1l[rr*64 + (kd ^ sw)];
                bf16x8 a1 = *(const bf16x8*)&R1l[rr*64 + ((32 + kd) ^ sw)];
                f32x4 c = mfma16(a1, aqv[1], mfma16(a0, aqv[0], zf));
                *(f32x4*)&pp[w][lr][jf*16 + 4*lkg] = c;
            }
#pragma unroll
            for (int j = 0; j < 4; ++j)
#pragma unroll
                for (int r = 0; r < 4; ++r) {
                    const int sof = 16*j + 4*lkg + r;
                    const int dt  = (s0 + sof) - (tb + lr);
                    const float v = pp[w][lr][sof + d15];
                    sc[j][r] += (dt <= 0) ? v : 0.0f;
                }
        }
        if (s0 >= tb - 61) {
#pragma unroll
            for (int jf = 0; jf < 5; ++jf) {
                const int rr = 48 - 16*w + jf*16 + lr;
                const int sw = (rr & 7) << 3;
                bf16x8 a0 = *(const bf16x8*)&R2l[rr*64 + (kd ^ sw)];
                bf16x8 a1 = *(const bf16x8*)&R2l[rr*64 + ((32 + kd) ^ sw)];
                f32x4 c = mfma16(a1, aqv2[1], mfma16(a0, aqv2[0], zf));
                *(f32x4*)&pp[w][lr][jf*16 + 4*lkg] = c;
            }
#pragma unroll
            for (int j = 0; j < 4; ++j)
#pragma unroll
                for (int r = 0; r < 4; ++r) {
                    const int sof = 16*j + 4*lkg + r;
                    const int dt  = (s0 + sof) - (tb + lr);
                    const float v = pp[w][lr][sof + d15];
                    sc[j][r] += (dt >= 2) ? v : 0.0f;
                }
        }

        float mx = fmaxf(fmaxf(fmaxf(sc[0][0], sc[0][1]), fmaxf(sc[0][2], sc[0][3])),
                         fmaxf(fmaxf(sc[1][0], sc[1][1]), fmaxf(sc[1][2], sc[1][3])));
        mx = fmaxf(mx, fmaxf(fmaxf(fmaxf(sc[2][0], sc[2][1]), fmaxf(sc[2][2], sc[2][3])),
                             fmaxf(fmaxf(sc[3][0], sc[3][1]), fmaxf(sc[3][2], sc[3][3]))));
        mx = fmaxf(mx, __shfl_xor(mx, 16, 64));
        mx = fmaxf(mx, __shfl_xor(mx, 32, 64));
        const float mnew = fmaxf(m_run, mx);
        const float fac = __expf(m_run - mnew);
        float sum = 0.0f;
#pragma unroll
        for (int j = 0; j < 4; ++j) {
            bf16x4 pk;
#pragma unroll
            for (int r = 0; r < 4; ++r) {
                const float p = __expf(sc[j][r] - mnew);
                sum += p;
                pk[r] = (bf16_t)p;
            }
            *(bf16x4*)&pl[w][lr][16*j + 4*lkg] = pk;
        }
        sum += __shfl_xor(sum, 16, 64);
        sum += __shfl_xor(sum, 32, 64);
        l_run = l_run * fac + sum;
        m_run = mnew;

#pragma unroll
        for (int r = 0; r < 4; ++r) {
            const float facq = __shfl(fac, 4*lkg + r, 64);
#pragma unroll
            for (int nf = 0; nf < 4; ++nf) oacc[nf][r] *= facq;
        }

        bf16x8 pa0 = *(const bf16x8*)(&pl[w][lr][kd]);
        bf16x8 pa1 = *(const bf16x8*)(&pl[w][lr][32 + kd]);
#pragma unroll
        for (int nf = 0; nf < 4; ++nf) {
            const int row = nf*16 + lr;
            const int sw = (row & 7) << 3;
            bf16x8 b0 = *(const bf16x8*)&Vl[row*64 + (kd ^ sw)];
            bf16x8 b1 = *(const bf16x8*)&Vl[row*64 + ((32 + kd) ^ sw)];
            oacc[nf] = mfma16(pa1, b1, mfma16(pa0, b0, oacc[nf]));
        }
        __syncthreads();
    }

    if (NSPLIT == 1) {
        const float linv = 1.0f / l_run;
#pragma unroll
        for (int r = 0; r < 4; ++r) {
            const float lq = __shfl(linv, 4*lkg + r, 64);
            const int t = tb + 4*lkg + r;
#pragma unroll
            for (int nf = 0; nf < 4; ++nf)
                AO[(size_t)(b*T_SEQ + t)*HID + h*HD + nf*16 + lr] = (bf16_t)(oacc[nf][r] * lq);
        }
    } else {
        float* po = PO + (((size_t)split*NB*NH + b*NH + h)*T_SEQ)*HD;
#pragma unroll
        for (int r = 0; r < 4; ++r)
#pragma unroll
            for (int nf = 0; nf < 4; ++nf)
                po[(size_t)(tb + 4*lkg + r)*HD + nf*16 + lr] = oacc[nf][r];
        if (lkg == 0) {
            float* ml = ML + ((size_t)split*NB*NH + b*NH + h)*2*T_SEQ;
            ml[tb + lr] = m_run;
            ml[T_SEQ + tb + lr] = l_run;
        }
    }
}

// Flash combine of the 2 KV-split partials -> AO bf16 [B,T,H*D].
__global__ __launch_bounds__(256) void combine_kernel(
    const float* __restrict__ PO, const float* __restrict__ ML,
    bf16_t* __restrict__ AO)
{
    const int idx = blockIdx.x * 256 + threadIdx.x;
    const int t = idx & (T_SEQ - 1);
    const int h = (idx >> 11) & (NH - 1);
    const int b = idx >> 15;
    const size_t poS = (size_t)NB*NH*T_SEQ*HD;
    const size_t mlS = (size_t)NB*NH*2*T_SEQ;
    const float* po1 = PO + (((size_t)b*NH + h)*T_SEQ + t)*HD;
    const float* po2 = po1 + poS;
    const float* ml1 = ML + ((size_t)b*NH + h)*2*T_SEQ;
    const float* ml2 = ml1 + mlS;
    const float m1 = ml1[t], l1 = ml1[T_SEQ + t];
    const float m2 = ml2[t], l2 = ml2[T_SEQ + t];
    const float M  = fmaxf(m1, m2);
    float f1 = __expf(m1 - M), f2 = __expf(m2 - M);
    const float linv = 1.0f / (f1*l1 + f2*l2);
    f1 *= linv; f2 *= linv;
    bf16_t* ao = AO + ((size_t)b*T_SEQ + t)*HID + h*HD;
#pragma unroll
    for (int d = 0; d < HD; d += 8) {
        f32x4 a0 = *(const f32x4*)(po1 + d), a1 = *(const f32x4*)(po1 + d + 4);
        f32x4 c0 = *(const f32x4*)(po2 + d), c1 = *(const f32x4*)(po2 + d + 4);
        bf16x8 o;
#pragma unroll
        for (int j = 0; j < 4; ++j) {
            o[j]     = (bf16_t)(f1*a0[j] + f2*c0[j]);
            o[4 + j] = (bf16_t)(f1*a1[j] + f2*c1[j]);
        }
        *(bf16x8*)(ao + d) = o;
    }
}

extern "C" void kernel_launch(void* const* d_in, const int* in_sizes, int n_in,
                              void* d_out, int out_size, void* d_ws, size_t ws_size,
                              hipStream_t stream) {
    const float* x    = (const float*)d_in[0];
    const float* pos  = (const float*)d_in[1];
    const float* Wq   = (const float*)d_in[2];
    const float* Wk   = (const float*)d_in[3];
    const float* Wv   = (const float*)d_in[4];
    const float* Wo   = (const float*)d_in[5];
    const float* Wrel = (const float*)d_in[6];
    const float* bu   = (const float*)d_in[7];
    const float* bv   = (const float*)d_in[8];

    // ws layout (bf16 elems, M1 = 1M):
    //  qb 0-4 | kb 4-8 | vtb 8-12 | rkb 12-14 | ab 14-18 (xb aliases ab) |
    //  pb 18-20 | wqb 20-21 | wkb 21-22 | wvb 22-23 | wob 23-24 | wrelb 24-25
    //  = 50 MiB base; then PO (67 MiB) + ML (1 MiB) if room for KV-split2.
    bf16_t* ws   = (bf16_t*)d_ws;
    const size_t M1 = 1024u * 1024u;
    bf16_t* qb    = ws;
    bf16_t* kb    = ws + 4*M1;
    bf16_t* vtb   = ws + 8*M1;
    bf16_t* rkb   = ws + 12*M1;
    bf16_t* ab    = ws + 14*M1;
    bf16_t* xb    = ab;
    bf16_t* pb    = ws + 18*M1;
    bf16_t* wqb   = ws + 20*M1;
    bf16_t* wkb   = ws + 21*M1;
    bf16_t* wvb   = ws + 22*M1;
    bf16_t* wob   = ws + 23*M1;
    bf16_t* wrelb = ws + 24*M1;

    const size_t baseBytes = 25*M1*2;
    const size_t poBytes = (size_t)2*NB*NH*T_SEQ*HD*4;
    const size_t mlBytes = (size_t)2*NB*NH*2*T_SEQ*4;
    float* PO = (float*)((char*)d_ws + baseBytes);
    float* ML = (float*)((char*)d_ws + baseBytes + poBytes);
    const bool split2 = ws_size >= baseBytes + poBytes + mlBytes;

    cvt_all<<<5632, 256, 0, stream>>>(x, pos, Wq, Wk, Wv, Wo, Wrel,
                                      xb, pb, wqb, wkb, wvb, wob, wrelb);

    gemm_bb<0><<<256, 256, 0, stream>>>(xb, wqb,   qb,  4096, 32);
    gemm_bb<0><<<256, 256, 0, stream>>>(xb, wkb,   kb,  4096, 32);
    gemm_bb<1><<<256, 256, 0, stream>>>(xb, wvb,   vtb, 4096, 32);
    gemm_bb<0><<<128, 256, 0, stream>>>(pb, wrelb, rkb, 2048, 16);

    if (split2) {
        attn_kernel<2><<<2048, 256, 0, stream>>>(qb, kb, vtb, rkb, bu, bv, ab, PO, ML, 256);
        combine_kernel<<<256, 256, 0, stream>>>(PO, ML, ab);
    } else {
        attn_kernel<1><<<1024, 256, 0, stream>>>(qb, kb, vtb, rkb, bu, bv, ab, nullptr, nullptr, 128);
    }

    gemm_bb<2><<<256, 256, 0, stream>>>(ab, wob, d_out, 4096, 32);
}